// Round 1
// baseline (46.259 us; speedup 1.0000x reference)
//
#include <hip/hip_runtime.h>

// Reference: loss = sum over (b,j) of ||kps[b,j,:]||_2 gated by (norm > half_body=1.0),
// divided by B*J. Input: [B=524288, J=17, D=3] float32. Output: 1 float32 scalar.

__global__ __launch_bounds__(256) void body_loss_kernel(
    const float4* __restrict__ p4, float* __restrict__ out,
    int nquads, float inv_norm) {
    // Each work item i covers 4 consecutive triples = 12 floats = 3 float4s.
    float acc = 0.0f;
    const int stride = gridDim.x * blockDim.x;
    for (int i = blockIdx.x * blockDim.x + threadIdx.x; i < nquads; i += stride) {
        const float4 v0 = p4[3 * i + 0];
        const float4 v1 = p4[3 * i + 1];
        const float4 v2 = p4[3 * i + 2];
        const float d0 = sqrtf(v0.x * v0.x + v0.y * v0.y + v0.z * v0.z);
        const float d1 = sqrtf(v0.w * v0.w + v1.x * v1.x + v1.y * v1.y);
        const float d2 = sqrtf(v1.z * v1.z + v1.w * v1.w + v2.x * v2.x);
        const float d3 = sqrtf(v2.y * v2.y + v2.z * v2.z + v2.w * v2.w);
        acc += (d0 > 1.0f ? d0 : 0.0f);
        acc += (d1 > 1.0f ? d1 : 0.0f);
        acc += (d2 > 1.0f ? d2 : 0.0f);
        acc += (d3 > 1.0f ? d3 : 0.0f);
    }

    // Wave (64-lane) butterfly reduce.
    #pragma unroll
    for (int off = 32; off > 0; off >>= 1)
        acc += __shfl_down(acc, off, 64);

    __shared__ float wsum[4];  // 256 threads = 4 waves
    const int lane = threadIdx.x & 63;
    const int wid  = threadIdx.x >> 6;
    if (lane == 0) wsum[wid] = acc;
    __syncthreads();
    if (threadIdx.x == 0) {
        const float s = wsum[0] + wsum[1] + wsum[2] + wsum[3];
        atomicAdd(out, s * inv_norm);  // device-scope by default on CDNA
    }
}

extern "C" void kernel_launch(void* const* d_in, const int* in_sizes, int n_in,
                              void* d_out, int out_size, void* d_ws, size_t ws_size,
                              hipStream_t stream) {
    const float* in = (const float*)d_in[0];
    float* out = (float*)d_out;

    const long long nfloats  = in_sizes[0];          // B*J*3 = 26,738,688
    const long long ntriples = nfloats / 3;          // B*J   = 8,912,896
    const int nquads = (int)(ntriples / 4);          // 2,228,224 (exactly divisible)
    const float inv_norm = 1.0f / (float)ntriples;

    // d_out is poisoned (0xAA) before timing and never re-zeroed between
    // replays — zero it ourselves every launch (graph-capture-safe async op).
    hipMemsetAsync(d_out, 0, sizeof(float), stream);

    const int block = 256;
    int grid = (nquads + block - 1) / block;
    if (grid > 2048) grid = 2048;
    body_loss_kernel<<<grid, block, 0, stream>>>(
        (const float4*)in, out, nquads, inv_norm);
}

// Round 2
// 23.540 us; speedup vs baseline: 1.9651x; 1.9651x over previous
//
#include <hip/hip_runtime.h>

// loss = sum_{b,j} ||kps[b,j,:]||_2 * (norm > 1.0) / (B*J)
// Input: [524288, 17, 3] fp32 = 26,738,688 floats. Output: 1 fp32 scalar.
//
// Kernel 1: grid-stride over 3072-float chunks. Three wave-dense float4
// global loads -> LDS -> per-thread 4 triples -> block partial -> d_ws[bid].
// Kernel 2: single block reduces the 2048 partials -> d_out. No memset needed.

#define GRID1 2048
#define BLOCK 256
#define CHUNK_F4 768   // 3072 floats per chunk = 256 threads * 12 floats

__global__ __launch_bounds__(BLOCK) void body_loss_partial(
    const float4* __restrict__ p4, float* __restrict__ partial, int nchunks) {
    __shared__ float4 lds[CHUNK_F4];
    const int t = threadIdx.x;
    float acc = 0.0f;

    for (int c = blockIdx.x; c < nchunks; c += GRID1) {
        const int base = c * CHUNK_F4;
        // Wave-dense: consecutive lanes read consecutive float4s per instruction.
        const float4 g0 = p4[base + t];
        const float4 g1 = p4[base + 256 + t];
        const float4 g2 = p4[base + 512 + t];
        __syncthreads();               // previous chunk's LDS reads done
        lds[t]       = g0;
        lds[256 + t] = g1;
        lds[512 + t] = g2;
        __syncthreads();
        const float4 v0 = lds[3 * t + 0];
        const float4 v1 = lds[3 * t + 1];
        const float4 v2 = lds[3 * t + 2];
        const float d0 = sqrtf(v0.x * v0.x + v0.y * v0.y + v0.z * v0.z);
        const float d1 = sqrtf(v0.w * v0.w + v1.x * v1.x + v1.y * v1.y);
        const float d2 = sqrtf(v1.z * v1.z + v1.w * v1.w + v2.x * v2.x);
        const float d3 = sqrtf(v2.y * v2.y + v2.z * v2.z + v2.w * v2.w);
        acc += (d0 > 1.0f ? d0 : 0.0f);
        acc += (d1 > 1.0f ? d1 : 0.0f);
        acc += (d2 > 1.0f ? d2 : 0.0f);
        acc += (d3 > 1.0f ? d3 : 0.0f);
    }

    // 64-lane butterfly reduce.
    #pragma unroll
    for (int off = 32; off > 0; off >>= 1)
        acc += __shfl_down(acc, off, 64);

    __shared__ float wsum[4];
    const int lane = t & 63, wid = t >> 6;
    if (lane == 0) wsum[wid] = acc;
    __syncthreads();
    if (t == 0)
        partial[blockIdx.x] = wsum[0] + wsum[1] + wsum[2] + wsum[3];
}

__global__ __launch_bounds__(BLOCK) void body_loss_final(
    const float* __restrict__ partial, float* __restrict__ out, float inv_norm) {
    const int t = threadIdx.x;
    float acc = 0.0f;
    #pragma unroll
    for (int k = 0; k < GRID1 / BLOCK; ++k)
        acc += partial[k * BLOCK + t];
    #pragma unroll
    for (int off = 32; off > 0; off >>= 1)
        acc += __shfl_down(acc, off, 64);
    __shared__ float wsum[4];
    const int lane = t & 63, wid = t >> 6;
    if (lane == 0) wsum[wid] = acc;
    __syncthreads();
    if (t == 0)
        out[0] = (wsum[0] + wsum[1] + wsum[2] + wsum[3]) * inv_norm;
}

extern "C" void kernel_launch(void* const* d_in, const int* in_sizes, int n_in,
                              void* d_out, int out_size, void* d_ws, size_t ws_size,
                              hipStream_t stream) {
    const float* in = (const float*)d_in[0];
    float* out = (float*)d_out;
    float* partial = (float*)d_ws;   // 2048 floats = 8 KB scratch

    const long long nfloats  = in_sizes[0];           // 26,738,688
    const long long ntriples = nfloats / 3;           // 8,912,896
    const int nchunks = (int)(nfloats / (CHUNK_F4 * 4));  // 8704 exact
    const float inv_norm = 1.0f / (float)ntriples;

    body_loss_partial<<<GRID1, BLOCK, 0, stream>>>(
        (const float4*)in, partial, nchunks);
    body_loss_final<<<1, BLOCK, 0, stream>>>(partial, out, inv_norm);
}

// Round 4
// 21.037 us; speedup vs baseline: 2.1989x; 1.1190x over previous
//
#include <hip/hip_runtime.h>

// loss = sum_{b,j} ||kps[b,j,:]||_2 * (norm > 1.0) / (B*J)
// Input: [524288, 17, 3] fp32 = 26,738,688 floats. Output: 1 fp32 scalar.
//
// Kernel 1: grid-stride over 3072-float chunks. Double-buffered LDS,
// ONE barrier per chunk, next chunk's 3 wave-dense float4 loads issued
// before the barrier (latency overlaps barrier-wait + compute).
// Kernel 2: single block reduces 2048 partials -> d_out. No memset needed.

#define GRID1 2048
#define BLOCK 256
#define CF4   768   // float4s per chunk = 3072 floats = 256 threads * 12 floats

// Native clang vector type: __builtin_nontemporal_load requires a vector of
// scalar types, not the HIP_vector_type struct.
typedef float vf4 __attribute__((ext_vector_type(4)));

__global__ __launch_bounds__(BLOCK) void body_loss_partial(
    const vf4* __restrict__ p4, float* __restrict__ partial, int nchunks) {
    __shared__ vf4 lds[2][CF4];
    const int t = threadIdx.x;
    float acc = 0.0f;

    int c = blockIdx.x;               // always < nchunks (8704 > 2048)
    {
        const vf4* g = p4 + (size_t)c * CF4;
        vf4 r0 = __builtin_nontemporal_load(&g[t]);
        vf4 r1 = __builtin_nontemporal_load(&g[256 + t]);
        vf4 r2 = __builtin_nontemporal_load(&g[512 + t]);
        int cur = 0;
        lds[0][t] = r0; lds[0][256 + t] = r1; lds[0][512 + t] = r2;

        int next = c + GRID1;
        while (true) {
            const bool have_next = next < nchunks;
            if (have_next) {
                const vf4* gn = p4 + (size_t)next * CF4;
                r0 = __builtin_nontemporal_load(&gn[t]);
                r1 = __builtin_nontemporal_load(&gn[256 + t]);
                r2 = __builtin_nontemporal_load(&gn[512 + t]);
            }
            __syncthreads();   // lds[cur] writes (end of prev iter) visible
            const vf4 v0 = lds[cur][3 * t + 0];
            const vf4 v1 = lds[cur][3 * t + 1];
            const vf4 v2 = lds[cur][3 * t + 2];
            const float d0 = sqrtf(v0.x * v0.x + v0.y * v0.y + v0.z * v0.z);
            const float d1 = sqrtf(v0.w * v0.w + v1.x * v1.x + v1.y * v1.y);
            const float d2 = sqrtf(v1.z * v1.z + v1.w * v1.w + v2.x * v2.x);
            const float d3 = sqrtf(v2.y * v2.y + v2.z * v2.z + v2.w * v2.w);
            acc += (d0 > 1.0f ? d0 : 0.0f);
            acc += (d1 > 1.0f ? d1 : 0.0f);
            acc += (d2 > 1.0f ? d2 : 0.0f);
            acc += (d3 > 1.0f ? d3 : 0.0f);
            if (!have_next) break;
            // Safe to overwrite lds[cur^1]: its readers (iter i-1) finished
            // their reads before this iteration's barrier.
            cur ^= 1;
            lds[cur][t] = r0; lds[cur][256 + t] = r1; lds[cur][512 + t] = r2;
            next += GRID1;
        }
    }

    // 64-lane butterfly reduce.
    #pragma unroll
    for (int off = 32; off > 0; off >>= 1)
        acc += __shfl_down(acc, off, 64);

    __shared__ float wsum[4];
    const int lane = t & 63, wid = t >> 6;
    if (lane == 0) wsum[wid] = acc;
    __syncthreads();
    if (t == 0)
        partial[blockIdx.x] = wsum[0] + wsum[1] + wsum[2] + wsum[3];
}

__global__ __launch_bounds__(BLOCK) void body_loss_final(
    const float* __restrict__ partial, float* __restrict__ out, float inv_norm) {
    const int t = threadIdx.x;
    float acc = 0.0f;
    #pragma unroll
    for (int k = 0; k < GRID1 / BLOCK; ++k)
        acc += partial[k * BLOCK + t];
    #pragma unroll
    for (int off = 32; off > 0; off >>= 1)
        acc += __shfl_down(acc, off, 64);
    __shared__ float wsum[4];
    const int lane = t & 63, wid = t >> 6;
    if (lane == 0) wsum[wid] = acc;
    __syncthreads();
    if (t == 0)
        out[0] = (wsum[0] + wsum[1] + wsum[2] + wsum[3]) * inv_norm;
}

extern "C" void kernel_launch(void* const* d_in, const int* in_sizes, int n_in,
                              void* d_out, int out_size, void* d_ws, size_t ws_size,
                              hipStream_t stream) {
    const float* in = (const float*)d_in[0];
    float* out = (float*)d_out;
    float* partial = (float*)d_ws;   // 2048 floats = 8 KB scratch

    const long long nfloats  = in_sizes[0];               // 26,738,688
    const long long ntriples = nfloats / 3;               // 8,912,896
    const int nchunks = (int)(nfloats / (CF4 * 4));       // 8704 exact
    const float inv_norm = 1.0f / (float)ntriples;

    body_loss_partial<<<GRID1, BLOCK, 0, stream>>>(
        (const vf4*)in, partial, nchunks);
    body_loss_final<<<1, BLOCK, 0, stream>>>(partial, out, inv_norm);
}